// Round 18
// baseline (72.356 us; speedup 1.0000x reference)
//
#include <hip/hip_runtime.h>

#define DEVINL __device__ __forceinline__

DEVINL float gelu_exact(float x){ return 0.5f * x * (1.0f + erff(x * 0.70710678118654752f)); }
DEVINL float lrelu02(float x){ return x >= 0.0f ? x : 0.2f * x; }

// B=4 S=16 N=400 -> 64 graph batches, 25600 node-rows, 1600 sequences
#define NN    400
#define NROWS 25600
#define NSEQ  1600

// ws byte offsets (all 16B-aligned, non-overlapping)
#define OFF_NBR  0u
#define OFF_CNT  320000u
#define OFF_HP1  321600u
#define OFF_ES1  1960000u
#define OFF_ED1  2369600u
#define OFF_HP2  2779200u
#define OFF_ES2  6056000u
#define OFF_ED2  6465600u

// K_A: block-split union kernel.
//   blocks [0,400):    sparse neighbor lists (one wave per row, f64 cosine)
//   blocks [400,500):  fused proj + GAT1-pre (hp1, es1, ed1), one thread/row
__global__ __launch_bounds__(256) void k_nbr_pre1(const float* __restrict__ emb,
    const float* __restrict__ x, const float* __restrict__ pw, const float* __restrict__ pb,
    const float* __restrict__ g1w, const float* __restrict__ as1, const float* __restrict__ ad1,
    unsigned short* __restrict__ nlist, int* __restrict__ cnt,
    float* __restrict__ hp1, float* __restrict__ es1, float* __restrict__ ed1){
  if (blockIdx.x < NN){
    const int i = blockIdx.x;
    const int lane = threadIdx.x;
    if (lane >= 64) return;
    double ai[16];
    double si = 0.0;
    #pragma unroll
    for (int k = 0; k < 16; k++){ ai[k] = (double)emb[i*16 + k]; si += ai[k]*ai[k]; }
    const double rni = 1.0 / sqrt(fmax(si, 1e-12));
    int base = 0;
    #pragma unroll
    for (int t = 0; t < 7; t++){
      const int j = t*64 + lane;
      bool valid = false;
      if (j < NN){
        double sj = 0.0, dp = 0.0;
        #pragma unroll
        for (int k = 0; k < 16; k++){
          double bv = (double)emb[j*16 + k];
          sj += bv*bv; dp += ai[k]*bv;
        }
        double c = dp * rni / sqrt(fmax(sj, 1e-12));
        valid = (c > 0.5);
      }
      unsigned long long bal = __ballot(valid);
      int pre = __popcll(bal & ((1ull << lane) - 1ull));
      if (valid) nlist[i*NN + base + pre] = (unsigned short)j;
      base += (int)__popcll(bal);
    }
    if (lane == 0) cnt[i] = base;
    return;
  }
  // ---- pre1 ----
  __shared__ float s_pw[48], s_pb[16], s_w[256], s_as[16], s_ad[16];
  const int tid = threadIdx.x;
  if (tid < 48) s_pw[tid] = pw[tid];
  if (tid < 16){ s_pb[tid] = pb[tid]; s_as[tid] = as1[tid]; s_ad[tid] = ad1[tid]; }
  s_w[tid] = g1w[tid];
  __syncthreads();
  const int row = (blockIdx.x - NN) * 256 + tid;
  if (row >= NROWS) return;
  float x0 = x[row*3+0], x1v = x[row*3+1], x2 = x[row*3+2];
  float h0[16];
  #pragma unroll
  for (int c = 0; c < 16; c++)
    h0[c] = s_pb[c] + x0 * s_pw[c] + x1v * s_pw[16+c] + x2 * s_pw[32+c];
  float hp[16];
  #pragma unroll
  for (int c = 0; c < 16; c++){
    float a = 0.f;
    #pragma unroll
    for (int k = 0; k < 16; k++) a += h0[k] * s_w[k*16 + c];
    hp[c] = a;
  }
  float4* hout = (float4*)(hp1 + (size_t)row * 16);
  hout[0] = make_float4(hp[0],hp[1],hp[2],hp[3]);
  hout[1] = make_float4(hp[4],hp[5],hp[6],hp[7]);
  hout[2] = make_float4(hp[8],hp[9],hp[10],hp[11]);
  hout[3] = make_float4(hp[12],hp[13],hp[14],hp[15]);
  #pragma unroll
  for (int h = 0; h < 4; h++){
    float es = 0.f, ed = 0.f;
    #pragma unroll
    for (int d = 0; d < 4; d++){ es += hp[h*4+d]*s_as[h*4+d]; ed += hp[h*4+d]*s_ad[h*4+d]; }
    es1[row*4 + h] = es;
    ed1[row*4 + h] = ed;
  }
}

// K_B: fused GAT1 (all 4 heads in one thread) + gelu + pre2 (hp2/es2/ed2).
__global__ __launch_bounds__(256) void k_gat1pre2(
    const float* __restrict__ hp1, const float* __restrict__ es1, const float* __restrict__ ed1,
    const unsigned short* __restrict__ nlist, const int* __restrict__ cnt,
    const float* __restrict__ g1b, const float* __restrict__ g2w,
    const float* __restrict__ as2, const float* __restrict__ ad2,
    float* __restrict__ hp2, float* __restrict__ es2, float* __restrict__ ed2){
  __shared__ float s_w[512], s_b1[16], s_as[32], s_ad[32];
  const int tid = threadIdx.x;
  s_w[tid] = g2w[tid]; s_w[tid+256] = g2w[tid+256];
  if (tid < 16) s_b1[tid] = g1b[tid];
  if (tid < 32){ s_as[tid] = as2[tid]; s_ad[tid] = ad2[tid]; }
  __syncthreads();
  const int row = blockIdx.x * 256 + tid;
  if (row >= NROWS) return;
  const int gb = row / NN;
  const int i  = row - gb * NN;
  const int n  = cnt[i];
  const unsigned short* nl = nlist + i * NN;
  const float4* esb = (const float4*)(es1 + (size_t)gb * NN * 4);
  const float*  hpb = hp1 + (size_t)gb * NN * 16;
  const float4 edv = *(const float4*)(ed1 + (size_t)row * 4);
  const float edr[4] = {edv.x, edv.y, edv.z, edv.w};
  float mx[4] = {-1e30f,-1e30f,-1e30f,-1e30f};
  for (int k0 = 0; k0 < n; k0 += 8){
    int jj[8]; float wv[8];
    #pragma unroll
    for (int u = 0; u < 8; u++){
      int kk = k0+u; jj[u] = (int)nl[kk < n ? kk : n-1]; wv[u] = (kk < n) ? 1.f : 0.f;
    }
    #pragma unroll
    for (int u = 0; u < 8; u++){
      float4 e4 = esb[jj[u]];
      mx[0] = fmaxf(mx[0], wv[u] > 0.5f ? e4.x : -1e30f);
      mx[1] = fmaxf(mx[1], wv[u] > 0.5f ? e4.y : -1e30f);
      mx[2] = fmaxf(mx[2], wv[u] > 0.5f ? e4.z : -1e30f);
      mx[3] = fmaxf(mx[3], wv[u] > 0.5f ? e4.w : -1e30f);
    }
  }
  float m[4];
  #pragma unroll
  for (int h = 0; h < 4; h++) m[h] = lrelu02(edr[h] + mx[h]);
  float den[4] = {0.f,0.f,0.f,0.f};
  float acc[16];
  #pragma unroll
  for (int d = 0; d < 16; d++) acc[d] = 0.f;
  for (int k0 = 0; k0 < n; k0 += 8){
    int jj[8]; float wv[8];
    #pragma unroll
    for (int u = 0; u < 8; u++){
      int kk = k0+u; jj[u] = (int)nl[kk < n ? kk : n-1]; wv[u] = (kk < n) ? 1.f : 0.f;
    }
    #pragma unroll
    for (int u = 0; u < 8; u++){
      float4 e4 = esb[jj[u]];
      const float4* hv = (const float4*)(hpb + (size_t)jj[u] * 16);
      float4 h0 = hv[0], h1 = hv[1], h2v = hv[2], h3 = hv[3];
      float p0 = wv[u] * __expf(lrelu02(edr[0]+e4.x) - m[0]); den[0] += p0;
      float p1 = wv[u] * __expf(lrelu02(edr[1]+e4.y) - m[1]); den[1] += p1;
      float p2 = wv[u] * __expf(lrelu02(edr[2]+e4.z) - m[2]); den[2] += p2;
      float p3 = wv[u] * __expf(lrelu02(edr[3]+e4.w) - m[3]); den[3] += p3;
      acc[0]  += p0*h0.x;  acc[1]  += p0*h0.y;  acc[2]  += p0*h0.z;  acc[3]  += p0*h0.w;
      acc[4]  += p1*h1.x;  acc[5]  += p1*h1.y;  acc[6]  += p1*h1.z;  acc[7]  += p1*h1.w;
      acc[8]  += p2*h2v.x; acc[9]  += p2*h2v.y; acc[10] += p2*h2v.z; acc[11] += p2*h2v.w;
      acc[12] += p3*h3.x;  acc[13] += p3*h3.y;  acc[14] += p3*h3.z;  acc[15] += p3*h3.w;
    }
  }
  float x1r[16];
  #pragma unroll
  for (int h = 0; h < 4; h++){
    float inv = 1.0f / den[h];
    #pragma unroll
    for (int d = 0; d < 4; d++)
      x1r[h*4+d] = gelu_exact(acc[h*4+d] * inv + s_b1[h*4+d]);
  }
  float hp[32];
  #pragma unroll
  for (int c = 0; c < 32; c++){
    float a = 0.f;
    #pragma unroll
    for (int k = 0; k < 16; k++) a += x1r[k] * s_w[k*32 + c];
    hp[c] = a;
  }
  float4* ho = (float4*)(hp2 + (size_t)row * 32);
  #pragma unroll
  for (int qd = 0; qd < 8; qd++)
    ho[qd] = make_float4(hp[qd*4], hp[qd*4+1], hp[qd*4+2], hp[qd*4+3]);
  #pragma unroll
  for (int h = 0; h < 4; h++){
    float es = 0.f, ed = 0.f;
    #pragma unroll
    for (int d = 0; d < 8; d++){ es += hp[h*8+d]*s_as[h*8+d]; ed += hp[h*8+d]*s_ad[h*8+d]; }
    es2[row*4 + h] = es;
    ed2[row*4 + h] = ed;
  }
}

struct TW { const float* p[20]; };
// order: 0 wq,1 bq,2 wk,3 bk,4 wv,5 bv,6 wo,7 bo,8 ln1g,9 ln1b,
//        10 fw1,11 fb1,12 fw2,13 fb2,14 ln2g,15 ln2b,16 rw1,17 rb1,18 rw2,19 rb2

// K_D v8: trans7 + guaranteed-vectorized LDS weight reads (float4 ds_read_b128).
// K/V/Q/A strides 33->36 (16B-aligned float4 attention ops), F2 stride 68.
// Rw1 read from global (L2) to keep total LDS ~77KB (2 blocks/CU).
__global__ __launch_bounds__(256) void k_trans8(
    const float* __restrict__ hp2, const float* __restrict__ es2,
    const float* __restrict__ ed2, const unsigned short* __restrict__ nlist,
    const int* __restrict__ cnt, const float* __restrict__ g2b,
    TW tw, float* __restrict__ out){
  __shared__ __align__(16) float Wq[1024], Wk[1024], Wv[1024], Wo[1024];
  __shared__ __align__(16) float Fw1[2048], Fw2[2048];
  __shared__ float Bq[32], Bk[32], Bv[32], Bo[32], L1g[32], L1b[32];
  __shared__ float Fb1[64], Fb2[32], L2g[32], L2b[32], Rb1v[16], Rw2[16];
  __shared__ float Gb2[32];
  __shared__ float Rb2s[1];
  __shared__ __align__(16) float SCR[4][2768]; // T@0(528,st33) K@528(st36) V@1104(st36) S@1680(Q/A st36, F2 st68)
  const int tid = threadIdx.x;
  const int w = tid >> 6, lane = tid & 63;
  for (int i = tid; i < 1024; i += 256){
    Wq[i] = tw.p[0][i]; Wk[i] = tw.p[2][i]; Wv[i] = tw.p[4][i]; Wo[i] = tw.p[6][i];
  }
  for (int i = tid; i < 2048; i += 256){ Fw1[i] = tw.p[10][i]; Fw2[i] = tw.p[12][i]; }
  if (tid < 32){
    Bq[tid] = tw.p[1][tid]; Bk[tid] = tw.p[3][tid]; Bv[tid] = tw.p[5][tid]; Bo[tid] = tw.p[7][tid];
    L1g[tid] = tw.p[8][tid]; L1b[tid] = tw.p[9][tid]; Fb2[tid] = tw.p[13][tid];
    L2g[tid] = tw.p[14][tid]; L2b[tid] = tw.p[15][tid];
    Gb2[tid] = g2b[tid];
  }
  if (tid < 64) Fb1[tid] = tw.p[11][tid];
  if (tid < 16){ Rb1v[tid] = tw.p[17][tid]; Rw2[tid] = tw.p[18][tid]; }
  if (tid == 0) Rb2s[0] = tw.p[19][0];
  __syncthreads();   // the only block barrier

  const float* R1g = tw.p[16];
  float* Tw = SCR[w];
  float* Kw = Tw + 528;
  float* Vw = Tw + 1104;
  float* Sw = Tw + 1680;
  const int p = blockIdx.x * 4 + w;
  const int s = lane >> 2, cg = lane & 3, ob = cg * 8;

  // ---- fused GAT2: lane (s, h=cg) computes T[s][ob..ob+8) for h2-row r=p*16+s ----
  {
    const int r  = p * 16 + s;
    const int gb = r / NN;
    const int i  = r - gb * NN;
    const int n  = cnt[i];
    const unsigned short* nl = nlist + i * NN;
    const int rbase = gb * NN;
    const float edh = ed2[(size_t)r * 4 + cg];
    float mx = -1e30f;
    for (int k0 = 0; k0 < n; k0 += 8){
      int jj[8]; float wv[8];
      #pragma unroll
      for (int u = 0; u < 8; u++){
        int kk = k0+u; jj[u] = (int)nl[kk < n ? kk : n-1]; wv[u] = (kk < n) ? 1.f : 0.f;
      }
      #pragma unroll
      for (int u = 0; u < 8; u++){
        float v = es2[(size_t)(rbase + jj[u]) * 4 + cg];
        mx = fmaxf(mx, wv[u] > 0.5f ? v : -1e30f);
      }
    }
    const float m = lrelu02(edh + mx);
    float den = 0.f;
    float acc[8];
    #pragma unroll
    for (int d = 0; d < 8; d++) acc[d] = 0.f;
    for (int k0 = 0; k0 < n; k0 += 8){
      int jj[8]; float wv[8], ev[8];
      #pragma unroll
      for (int u = 0; u < 8; u++){
        int kk = k0+u; jj[u] = (int)nl[kk < n ? kk : n-1]; wv[u] = (kk < n) ? 1.f : 0.f;
      }
      #pragma unroll
      for (int u = 0; u < 8; u++) ev[u] = es2[(size_t)(rbase + jj[u]) * 4 + cg];
      #pragma unroll
      for (int u = 0; u < 8; u++){
        float pv = wv[u] * __expf(lrelu02(edh + ev[u]) - m);
        den += pv;
        const float4* vp = (const float4*)(hp2 + (size_t)(rbase + jj[u]) * 32 + cg * 8);
        float4 v0 = vp[0], v1 = vp[1];
        acc[0] += pv*v0.x; acc[1] += pv*v0.y; acc[2] += pv*v0.z; acc[3] += pv*v0.w;
        acc[4] += pv*v1.x; acc[5] += pv*v1.y; acc[6] += pv*v1.z; acc[7] += pv*v1.w;
      }
    }
    const float invd = 1.0f / den;
    float* tr = Tw + s*33 + ob;
    #pragma unroll
    for (int u = 0; u < 8; u++) tr[u] = acc[u] * invd + Gb2[ob + u];
  }
  // ---- QKV projections (float4 LDS weight reads) ----
  float q[8], kk[8], vv[8];
  #pragma unroll
  for (int u = 0; u < 8; u++){ q[u] = Bq[ob+u]; kk[u] = Bk[ob+u]; vv[u] = Bv[ob+u]; }
  for (int f = 0; f < 32; f++){
    float tv = Tw[s*33 + f];
    const float4* wq4 = (const float4*)&Wq[f*32 + ob];
    const float4* wk4 = (const float4*)&Wk[f*32 + ob];
    const float4* wv4 = (const float4*)&Wv[f*32 + ob];
    float4 qa = wq4[0], qb = wq4[1];
    float4 ka = wk4[0], kb = wk4[1];
    float4 va = wv4[0], vb = wv4[1];
    q[0]  += tv*qa.x; q[1]  += tv*qa.y; q[2]  += tv*qa.z; q[3]  += tv*qa.w;
    q[4]  += tv*qb.x; q[5]  += tv*qb.y; q[6]  += tv*qb.z; q[7]  += tv*qb.w;
    kk[0] += tv*ka.x; kk[1] += tv*ka.y; kk[2] += tv*ka.z; kk[3] += tv*ka.w;
    kk[4] += tv*kb.x; kk[5] += tv*kb.y; kk[6] += tv*kb.z; kk[7] += tv*kb.w;
    vv[0] += tv*va.x; vv[1] += tv*va.y; vv[2] += tv*va.z; vv[3] += tv*va.w;
    vv[4] += tv*vb.x; vv[5] += tv*vb.y; vv[6] += tv*vb.z; vv[7] += tv*vb.w;
  }
  *(float4*)&Sw[s*36 + ob]     = make_float4(q[0],q[1],q[2],q[3]);
  *(float4*)&Sw[s*36 + ob + 4] = make_float4(q[4],q[5],q[6],q[7]);
  *(float4*)&Kw[s*36 + ob]     = make_float4(kk[0],kk[1],kk[2],kk[3]);
  *(float4*)&Kw[s*36 + ob + 4] = make_float4(kk[4],kk[5],kk[6],kk[7]);
  *(float4*)&Vw[s*36 + ob]     = make_float4(vv[0],vv[1],vv[2],vv[3]);
  *(float4*)&Vw[s*36 + ob + 4] = make_float4(vv[4],vv[5],vv[6],vv[7]);
  // ---- attention: lane -> (h = lane>>5, i = (lane>>1)&15, half = lane&1) ----
  const int ai = (lane >> 1) & 15;
  const int hb = (lane >> 5) * 16 + (lane & 1) * 8;
  float4 qr0 = *(const float4*)&Sw[ai*36 + hb];
  float4 qr1 = *(const float4*)&Sw[ai*36 + hb + 4];
  float sc[16];
  float mx = -1e30f;
  #pragma unroll
  for (int j = 0; j < 16; j++){
    float4 k0 = *(const float4*)&Kw[j*36 + hb];
    float4 k1 = *(const float4*)&Kw[j*36 + hb + 4];
    float d = qr0.x*k0.x + qr0.y*k0.y + qr0.z*k0.z + qr0.w*k0.w
            + qr1.x*k1.x + qr1.y*k1.y + qr1.z*k1.z + qr1.w*k1.w;
    d += __shfl_xor(d, 1);
    d *= 0.25f;
    sc[j] = d;
    mx = fmaxf(mx, d);
  }
  float den = 0.f;
  #pragma unroll
  for (int j = 0; j < 16; j++){ sc[j] = __expf(sc[j] - mx); den += sc[j]; }
  const float ainv = 1.0f / den;
  float at[8];
  #pragma unroll
  for (int u = 0; u < 8; u++) at[u] = 0.f;
  #pragma unroll
  for (int j = 0; j < 16; j++){
    float al = sc[j];
    float4 v0 = *(const float4*)&Vw[j*36 + hb];
    float4 v1 = *(const float4*)&Vw[j*36 + hb + 4];
    at[0] += al*v0.x; at[1] += al*v0.y; at[2] += al*v0.z; at[3] += al*v0.w;
    at[4] += al*v1.x; at[5] += al*v1.y; at[6] += al*v1.z; at[7] += al*v1.w;
  }
  *(float4*)&Sw[ai*36 + hb]     = make_float4(at[0]*ainv, at[1]*ainv, at[2]*ainv, at[3]*ainv);
  *(float4*)&Sw[ai*36 + hb + 4] = make_float4(at[4]*ainv, at[5]*ainv, at[6]*ainv, at[7]*ainv);
  // ---- out-proj (float4 Wo) + residual + LN1 ----
  float xr[8];
  #pragma unroll
  for (int u = 0; u < 8; u++) xr[u] = Bo[ob + u];
  for (int i2 = 0; i2 < 32; i2++){
    float av = Sw[s*36 + i2];
    const float4* wo4 = (const float4*)&Wo[i2*32 + ob];
    float4 oa = wo4[0], obv = wo4[1];
    xr[0] += av*oa.x;  xr[1] += av*oa.y;  xr[2] += av*oa.z;  xr[3] += av*oa.w;
    xr[4] += av*obv.x; xr[5] += av*obv.y; xr[6] += av*obv.z; xr[7] += av*obv.w;
  }
  #pragma unroll
  for (int u = 0; u < 8; u++) xr[u] += Tw[s*33 + ob + u];
  float sm = 0.f, sq = 0.f;
  #pragma unroll
  for (int u = 0; u < 8; u++){ sm += xr[u]; sq += xr[u]*xr[u]; }
  sm += __shfl_xor(sm, 1); sq += __shfl_xor(sq, 1);
  sm += __shfl_xor(sm, 2); sq += __shfl_xor(sq, 2);
  {
    float mean = sm * (1.f/32.f);
    float var  = sq * (1.f/32.f) - mean*mean;
    float rinv = 1.0f / sqrtf(var + 1e-3f);
    #pragma unroll
    for (int u = 0; u < 8; u++)
      Tw[s*33 + ob + u] = (xr[u] - mean) * rinv * L1g[ob+u] + L1b[ob+u];
  }
  // ---- FF1 (float4 Fw1) -> F2 in S (stride 68; Q/A dead) ----
  {
    const int cb = cg * 16;
    float fa[16];
    #pragma unroll
    for (int t = 0; t < 16; t++) fa[t] = Fb1[cb + t];
    for (int f = 0; f < 32; f++){
      float tv = Tw[s*33 + f];
      const float4* w4 = (const float4*)&Fw1[f*64 + cb];
      float4 a0 = w4[0], a1 = w4[1], a2 = w4[2], a3 = w4[3];
      fa[0]  += tv*a0.x; fa[1]  += tv*a0.y; fa[2]  += tv*a0.z; fa[3]  += tv*a0.w;
      fa[4]  += tv*a1.x; fa[5]  += tv*a1.y; fa[6]  += tv*a1.z; fa[7]  += tv*a1.w;
      fa[8]  += tv*a2.x; fa[9]  += tv*a2.y; fa[10] += tv*a2.z; fa[11] += tv*a2.w;
      fa[12] += tv*a3.x; fa[13] += tv*a3.y; fa[14] += tv*a3.z; fa[15] += tv*a3.w;
    }
    *(float4*)&Sw[s*68 + cb]      = make_float4(gelu_exact(fa[0]),  gelu_exact(fa[1]),  gelu_exact(fa[2]),  gelu_exact(fa[3]));
    *(float4*)&Sw[s*68 + cb + 4]  = make_float4(gelu_exact(fa[4]),  gelu_exact(fa[5]),  gelu_exact(fa[6]),  gelu_exact(fa[7]));
    *(float4*)&Sw[s*68 + cb + 8]  = make_float4(gelu_exact(fa[8]),  gelu_exact(fa[9]),  gelu_exact(fa[10]), gelu_exact(fa[11]));
    *(float4*)&Sw[s*68 + cb + 12] = make_float4(gelu_exact(fa[12]), gelu_exact(fa[13]), gelu_exact(fa[14]), gelu_exact(fa[15]));
  }
  // ---- FF2 (float4 Fw2) + residual + LN2 ----
  float y[8];
  #pragma unroll
  for (int u = 0; u < 8; u++) y[u] = Fb2[ob + u];
  for (int c = 0; c < 64; c++){
    float fv = Sw[s*68 + c];
    const float4* w4 = (const float4*)&Fw2[c*32 + ob];
    float4 a = w4[0], b2 = w4[1];
    y[0] += fv*a.x;  y[1] += fv*a.y;  y[2] += fv*a.z;  y[3] += fv*a.w;
    y[4] += fv*b2.x; y[5] += fv*b2.y; y[6] += fv*b2.z; y[7] += fv*b2.w;
  }
  #pragma unroll
  for (int u = 0; u < 8; u++) y[u] += Tw[s*33 + ob + u];
  sm = 0.f; sq = 0.f;
  #pragma unroll
  for (int u = 0; u < 8; u++){ sm += y[u]; sq += y[u]*y[u]; }
  sm += __shfl_xor(sm, 1); sq += __shfl_xor(sq, 1);
  sm += __shfl_xor(sm, 2); sq += __shfl_xor(sq, 2);
  float mean2 = sm * (1.f/32.f);
  float var2  = sq * (1.f/32.f) - mean2*mean2;
  float rinv2 = 1.0f / sqrtf(var2 + 1e-3f);
  // mean over the 16 tokens (butterfly over s bits: 4,8,16,32)
  float mv[8];
  #pragma unroll
  for (int u = 0; u < 8; u++){
    float v = (y[u] - mean2) * rinv2 * L2g[ob+u] + L2b[ob+u];
    v += __shfl_xor(v, 4);  v += __shfl_xor(v, 8);
    v += __shfl_xor(v, 16); v += __shfl_xor(v, 32);
    mv[u] = v * (1.f/16.f);
  }
  if (s == 0){
    #pragma unroll
    for (int u = 0; u < 8; u++) Tw[ob + u] = mv[u];   // M into T row 0
  }
  // ---- readout (t = lane&15; Rw1 from global/L2) ----
  const int t = lane & 15;
  float hid = Rb1v[t];
  for (int o2 = 0; o2 < 32; o2++) hid += Tw[o2] * R1g[o2*16 + t];
  hid = gelu_exact(hid) * Rw2[t];
  hid += __shfl_xor(hid, 1); hid += __shfl_xor(hid, 2);
  hid += __shfl_xor(hid, 4); hid += __shfl_xor(hid, 8);
  if (lane == 0) out[p] = hid + Rb2s[0];
}

extern "C" void kernel_launch(void* const* d_in, const int* in_sizes, int n_in,
                              void* d_out, int out_size, void* d_ws, size_t ws_size,
                              hipStream_t stream){
  const float* x    = (const float*)d_in[0];
  const float* adj  = (const float*)d_in[1];
  const float* pw   = (const float*)d_in[2];
  const float* pb   = (const float*)d_in[3];
  const float* g1w  = (const float*)d_in[4];
  const float* g1as = (const float*)d_in[5];
  const float* g1ad = (const float*)d_in[6];
  const float* g1b  = (const float*)d_in[7];
  const float* g2w  = (const float*)d_in[8];
  const float* g2as = (const float*)d_in[9];
  const float* g2ad = (const float*)d_in[10];
  const float* g2b  = (const float*)d_in[11];

  char* ws = (char*)d_ws;
  unsigned short* nlist = (unsigned short*)(ws + OFF_NBR);
  int*   cnt = (int*)(ws + OFF_CNT);
  float* hp1 = (float*)(ws + OFF_HP1);
  float* es1 = (float*)(ws + OFF_ES1);
  float* ed1 = (float*)(ws + OFF_ED1);
  float* hp2 = (float*)(ws + OFF_HP2);
  float* es2 = (float*)(ws + OFF_ES2);
  float* ed2 = (float*)(ws + OFF_ED2);

  TW tw;
  for (int t = 0; t < 20; t++) tw.p[t] = (const float*)d_in[12 + t];

  hipLaunchKernelGGL(k_nbr_pre1, dim3(NN + 100), dim3(256), 0, stream,
                     adj, x, pw, pb, g1w, g1as, g1ad, nlist, cnt, hp1, es1, ed1);
  hipLaunchKernelGGL(k_gat1pre2, dim3(100), dim3(256), 0, stream,
                     hp1, es1, ed1, nlist, cnt, g1b, g2w, g2as, g2ad, hp2, es2, ed2);
  hipLaunchKernelGGL(k_trans8, dim3(NSEQ/4), dim3(256), 0, stream,
                     hp2, es2, ed2, nlist, cnt, g2b, tw, (float*)d_out);
}

// Round 19
// 65.007 us; speedup vs baseline: 1.1130x; 1.1130x over previous
//
#include <hip/hip_runtime.h>

#define DEVINL __device__ __forceinline__

DEVINL float gelu_exact(float x){ return 0.5f * x * (1.0f + erff(x * 0.70710678118654752f)); }
DEVINL float lrelu02(float x){ return x >= 0.0f ? x : 0.2f * x; }

// B=4 S=16 N=400 -> 64 graph batches, 25600 node-rows, 1600 sequences
#define NN    400
#define NROWS 25600
#define NSEQ  1600

// ws byte offsets (all 16B-aligned, non-overlapping)
#define OFF_NBR  0u
#define OFF_CNT  320000u
#define OFF_HP1  321600u
#define OFF_ES1  1960000u
#define OFF_ED1  2369600u
#define OFF_HP2  2779200u
#define OFF_ES2  6056000u
#define OFF_ED2  6465600u

// K_A: block-split union kernel.
//   blocks [0,400):    sparse neighbor lists (one wave per row, f64 cosine)
//   blocks [400,500):  fused proj + GAT1-pre (hp1, es1, ed1), one thread/row
__global__ __launch_bounds__(256) void k_nbr_pre1(const float* __restrict__ emb,
    const float* __restrict__ x, const float* __restrict__ pw, const float* __restrict__ pb,
    const float* __restrict__ g1w, const float* __restrict__ as1, const float* __restrict__ ad1,
    unsigned short* __restrict__ nlist, int* __restrict__ cnt,
    float* __restrict__ hp1, float* __restrict__ es1, float* __restrict__ ed1){
  if (blockIdx.x < NN){
    const int i = blockIdx.x;
    const int lane = threadIdx.x;
    if (lane >= 64) return;
    double ai[16];
    double si = 0.0;
    #pragma unroll
    for (int k = 0; k < 16; k++){ ai[k] = (double)emb[i*16 + k]; si += ai[k]*ai[k]; }
    const double rni = 1.0 / sqrt(fmax(si, 1e-12));
    int base = 0;
    #pragma unroll
    for (int t = 0; t < 7; t++){
      const int j = t*64 + lane;
      bool valid = false;
      if (j < NN){
        double sj = 0.0, dp = 0.0;
        #pragma unroll
        for (int k = 0; k < 16; k++){
          double bv = (double)emb[j*16 + k];
          sj += bv*bv; dp += ai[k]*bv;
        }
        double c = dp * rni / sqrt(fmax(sj, 1e-12));
        valid = (c > 0.5);
      }
      unsigned long long bal = __ballot(valid);
      int pre = __popcll(bal & ((1ull << lane) - 1ull));
      if (valid) nlist[i*NN + base + pre] = (unsigned short)j;
      base += (int)__popcll(bal);
    }
    if (lane == 0) cnt[i] = base;
    return;
  }
  // ---- pre1 ----
  __shared__ float s_pw[48], s_pb[16], s_w[256], s_as[16], s_ad[16];
  const int tid = threadIdx.x;
  if (tid < 48) s_pw[tid] = pw[tid];
  if (tid < 16){ s_pb[tid] = pb[tid]; s_as[tid] = as1[tid]; s_ad[tid] = ad1[tid]; }
  s_w[tid] = g1w[tid];
  __syncthreads();
  const int row = (blockIdx.x - NN) * 256 + tid;
  if (row >= NROWS) return;
  float x0 = x[row*3+0], x1v = x[row*3+1], x2 = x[row*3+2];
  float h0[16];
  #pragma unroll
  for (int c = 0; c < 16; c++)
    h0[c] = s_pb[c] + x0 * s_pw[c] + x1v * s_pw[16+c] + x2 * s_pw[32+c];
  float hp[16];
  #pragma unroll
  for (int c = 0; c < 16; c++){
    float a = 0.f;
    #pragma unroll
    for (int k = 0; k < 16; k++) a += h0[k] * s_w[k*16 + c];
    hp[c] = a;
  }
  float4* hout = (float4*)(hp1 + (size_t)row * 16);
  hout[0] = make_float4(hp[0],hp[1],hp[2],hp[3]);
  hout[1] = make_float4(hp[4],hp[5],hp[6],hp[7]);
  hout[2] = make_float4(hp[8],hp[9],hp[10],hp[11]);
  hout[3] = make_float4(hp[12],hp[13],hp[14],hp[15]);
  #pragma unroll
  for (int h = 0; h < 4; h++){
    float es = 0.f, ed = 0.f;
    #pragma unroll
    for (int d = 0; d < 4; d++){ es += hp[h*4+d]*s_as[h*4+d]; ed += hp[h*4+d]*s_ad[h*4+d]; }
    es1[row*4 + h] = es;
    ed1[row*4 + h] = ed;
  }
}

// K_B: fused GAT1 (all 4 heads in one thread) + gelu + pre2 (hp2/es2/ed2).
__global__ __launch_bounds__(256) void k_gat1pre2(
    const float* __restrict__ hp1, const float* __restrict__ es1, const float* __restrict__ ed1,
    const unsigned short* __restrict__ nlist, const int* __restrict__ cnt,
    const float* __restrict__ g1b, const float* __restrict__ g2w,
    const float* __restrict__ as2, const float* __restrict__ ad2,
    float* __restrict__ hp2, float* __restrict__ es2, float* __restrict__ ed2){
  __shared__ float s_w[512], s_b1[16], s_as[32], s_ad[32];
  const int tid = threadIdx.x;
  s_w[tid] = g2w[tid]; s_w[tid+256] = g2w[tid+256];
  if (tid < 16) s_b1[tid] = g1b[tid];
  if (tid < 32){ s_as[tid] = as2[tid]; s_ad[tid] = ad2[tid]; }
  __syncthreads();
  const int row = blockIdx.x * 256 + tid;
  if (row >= NROWS) return;
  const int gb = row / NN;
  const int i  = row - gb * NN;
  const int n  = cnt[i];
  const unsigned short* nl = nlist + i * NN;
  const float4* esb = (const float4*)(es1 + (size_t)gb * NN * 4);
  const float*  hpb = hp1 + (size_t)gb * NN * 16;
  const float4 edv = *(const float4*)(ed1 + (size_t)row * 4);
  const float edr[4] = {edv.x, edv.y, edv.z, edv.w};
  float mx[4] = {-1e30f,-1e30f,-1e30f,-1e30f};
  for (int k0 = 0; k0 < n; k0 += 8){
    int jj[8]; float wv[8];
    #pragma unroll
    for (int u = 0; u < 8; u++){
      int kk = k0+u; jj[u] = (int)nl[kk < n ? kk : n-1]; wv[u] = (kk < n) ? 1.f : 0.f;
    }
    #pragma unroll
    for (int u = 0; u < 8; u++){
      float4 e4 = esb[jj[u]];
      mx[0] = fmaxf(mx[0], wv[u] > 0.5f ? e4.x : -1e30f);
      mx[1] = fmaxf(mx[1], wv[u] > 0.5f ? e4.y : -1e30f);
      mx[2] = fmaxf(mx[2], wv[u] > 0.5f ? e4.z : -1e30f);
      mx[3] = fmaxf(mx[3], wv[u] > 0.5f ? e4.w : -1e30f);
    }
  }
  float m[4];
  #pragma unroll
  for (int h = 0; h < 4; h++) m[h] = lrelu02(edr[h] + mx[h]);
  float den[4] = {0.f,0.f,0.f,0.f};
  float acc[16];
  #pragma unroll
  for (int d = 0; d < 16; d++) acc[d] = 0.f;
  for (int k0 = 0; k0 < n; k0 += 8){
    int jj[8]; float wv[8];
    #pragma unroll
    for (int u = 0; u < 8; u++){
      int kk = k0+u; jj[u] = (int)nl[kk < n ? kk : n-1]; wv[u] = (kk < n) ? 1.f : 0.f;
    }
    #pragma unroll
    for (int u = 0; u < 8; u++){
      float4 e4 = esb[jj[u]];
      const float4* hv = (const float4*)(hpb + (size_t)jj[u] * 16);
      float4 h0 = hv[0], h1 = hv[1], h2v = hv[2], h3 = hv[3];
      float p0 = wv[u] * __expf(lrelu02(edr[0]+e4.x) - m[0]); den[0] += p0;
      float p1 = wv[u] * __expf(lrelu02(edr[1]+e4.y) - m[1]); den[1] += p1;
      float p2 = wv[u] * __expf(lrelu02(edr[2]+e4.z) - m[2]); den[2] += p2;
      float p3 = wv[u] * __expf(lrelu02(edr[3]+e4.w) - m[3]); den[3] += p3;
      acc[0]  += p0*h0.x;  acc[1]  += p0*h0.y;  acc[2]  += p0*h0.z;  acc[3]  += p0*h0.w;
      acc[4]  += p1*h1.x;  acc[5]  += p1*h1.y;  acc[6]  += p1*h1.z;  acc[7]  += p1*h1.w;
      acc[8]  += p2*h2v.x; acc[9]  += p2*h2v.y; acc[10] += p2*h2v.z; acc[11] += p2*h2v.w;
      acc[12] += p3*h3.x;  acc[13] += p3*h3.y;  acc[14] += p3*h3.z;  acc[15] += p3*h3.w;
    }
  }
  float x1r[16];
  #pragma unroll
  for (int h = 0; h < 4; h++){
    float inv = 1.0f / den[h];
    #pragma unroll
    for (int d = 0; d < 4; d++)
      x1r[h*4+d] = gelu_exact(acc[h*4+d] * inv + s_b1[h*4+d]);
  }
  float hp[32];
  #pragma unroll
  for (int c = 0; c < 32; c++){
    float a = 0.f;
    #pragma unroll
    for (int k = 0; k < 16; k++) a += x1r[k] * s_w[k*32 + c];
    hp[c] = a;
  }
  float4* ho = (float4*)(hp2 + (size_t)row * 32);
  #pragma unroll
  for (int qd = 0; qd < 8; qd++)
    ho[qd] = make_float4(hp[qd*4], hp[qd*4+1], hp[qd*4+2], hp[qd*4+3]);
  #pragma unroll
  for (int h = 0; h < 4; h++){
    float es = 0.f, ed = 0.f;
    #pragma unroll
    for (int d = 0; d < 8; d++){ es += hp[h*8+d]*s_as[h*8+d]; ed += hp[h*8+d]*s_ad[h*8+d]; }
    es2[row*4 + h] = es;
    ed2[row*4 + h] = ed;
  }
}

struct TW { const float* p[20]; };
// order: 0 wq,1 bq,2 wk,3 bk,4 wv,5 bv,6 wo,7 bo,8 ln1g,9 ln1b,
//        10 fw1,11 fb1,12 fw2,13 fb2,14 ln2g,15 ln2b,16 rw1,17 rb1,18 rw2,19 rb2

// K_D v7b (round-17 measured best): trans3 + FUSED sparse GAT2 with correct
// reshape mapping: token s of sequence p is h2 flat row r = p*16+s;
// that row's graph-batch gb = r/400, node i = r%400 (per-LANE).
__global__ __launch_bounds__(256) void k_trans7(
    const float* __restrict__ hp2, const float* __restrict__ es2,
    const float* __restrict__ ed2, const unsigned short* __restrict__ nlist,
    const int* __restrict__ cnt, const float* __restrict__ g2b,
    TW tw, float* __restrict__ out){
  __shared__ float Wq[1024], Wk[1024], Wv[1024], Wo[1024];
  __shared__ float Fw1[2048], Fw2[2048], Rw1[512];
  __shared__ float Bq[32], Bk[32], Bv[32], Bo[32], L1g[32], L1b[32];
  __shared__ float Fb1[64], Fb2[32], L2g[32], L2b[32], Rb1v[16], Rw2[16];
  __shared__ float Gb2[32];
  __shared__ float Rb2s[1];
  __shared__ float SCR[4][2640];   // per-wave: T 528 | K 528 | V 528 | S 1056
  const int tid = threadIdx.x;
  const int w = tid >> 6, lane = tid & 63;
  for (int i = tid; i < 1024; i += 256){
    Wq[i] = tw.p[0][i]; Wk[i] = tw.p[2][i]; Wv[i] = tw.p[4][i]; Wo[i] = tw.p[6][i];
  }
  for (int i = tid; i < 2048; i += 256){ Fw1[i] = tw.p[10][i]; Fw2[i] = tw.p[12][i]; }
  for (int i = tid; i < 512; i += 256) Rw1[i] = tw.p[16][i];
  if (tid < 32){
    Bq[tid] = tw.p[1][tid]; Bk[tid] = tw.p[3][tid]; Bv[tid] = tw.p[5][tid]; Bo[tid] = tw.p[7][tid];
    L1g[tid] = tw.p[8][tid]; L1b[tid] = tw.p[9][tid]; Fb2[tid] = tw.p[13][tid];
    L2g[tid] = tw.p[14][tid]; L2b[tid] = tw.p[15][tid];
    Gb2[tid] = g2b[tid];
  }
  if (tid < 64) Fb1[tid] = tw.p[11][tid];
  if (tid < 16){ Rb1v[tid] = tw.p[17][tid]; Rw2[tid] = tw.p[18][tid]; }
  if (tid == 0) Rb2s[0] = tw.p[19][0];
  __syncthreads();   // the only block barrier

  float* Tw = SCR[w];
  float* Kw = Tw + 528;
  float* Vw = Tw + 1056;
  float* Sw = Tw + 1584;
  const int p = blockIdx.x * 4 + w;
  const int s = lane >> 2, cg = lane & 3, ob = cg * 8;

  // ---- fused GAT2: lane (s, h=cg) computes T[s][ob..ob+8) for h2-row r=p*16+s ----
  {
    const int r  = p * 16 + s;
    const int gb = r / NN;               // graph batch of this row
    const int i  = r - gb * NN;          // node id of this row
    const int n  = cnt[i];
    const unsigned short* nl = nlist + i * NN;
    const int rbase = gb * NN;
    const float edh = ed2[(size_t)r * 4 + cg];
    float mx = -1e30f;
    for (int k0 = 0; k0 < n; k0 += 8){
      int jj[8]; float wv[8];
      #pragma unroll
      for (int u = 0; u < 8; u++){
        int kk = k0+u; jj[u] = (int)nl[kk < n ? kk : n-1]; wv[u] = (kk < n) ? 1.f : 0.f;
      }
      #pragma unroll
      for (int u = 0; u < 8; u++){
        float v = es2[(size_t)(rbase + jj[u]) * 4 + cg];
        mx = fmaxf(mx, wv[u] > 0.5f ? v : -1e30f);
      }
    }
    const float m = lrelu02(edh + mx);
    float den = 0.f;
    float acc[8];
    #pragma unroll
    for (int d = 0; d < 8; d++) acc[d] = 0.f;
    for (int k0 = 0; k0 < n; k0 += 8){
      int jj[8]; float wv[8], ev[8];
      #pragma unroll
      for (int u = 0; u < 8; u++){
        int kk = k0+u; jj[u] = (int)nl[kk < n ? kk : n-1]; wv[u] = (kk < n) ? 1.f : 0.f;
      }
      #pragma unroll
      for (int u = 0; u < 8; u++) ev[u] = es2[(size_t)(rbase + jj[u]) * 4 + cg];
      #pragma unroll
      for (int u = 0; u < 8; u++){
        float pv = wv[u] * __expf(lrelu02(edh + ev[u]) - m);
        den += pv;
        const float4* vp = (const float4*)(hp2 + (size_t)(rbase + jj[u]) * 32 + cg * 8);
        float4 v0 = vp[0], v1 = vp[1];
        acc[0] += pv*v0.x; acc[1] += pv*v0.y; acc[2] += pv*v0.z; acc[3] += pv*v0.w;
        acc[4] += pv*v1.x; acc[5] += pv*v1.y; acc[6] += pv*v1.z; acc[7] += pv*v1.w;
      }
    }
    const float invd = 1.0f / den;
    float* tr = Tw + s*33 + ob;
    #pragma unroll
    for (int u = 0; u < 8; u++) tr[u] = acc[u] * invd + Gb2[ob + u];
  }
  // ---- transformer (verbatim trans3 from here) ----
  float q[8], kk[8], vv[8];
  #pragma unroll
  for (int u = 0; u < 8; u++){ q[u] = Bq[ob+u]; kk[u] = Bk[ob+u]; vv[u] = Bv[ob+u]; }
  for (int f = 0; f < 32; f++){
    float tv = Tw[s*33 + f];
    #pragma unroll
    for (int u = 0; u < 8; u++){
      q[u]  += tv * Wq[f*32 + ob + u];
      kk[u] += tv * Wk[f*32 + ob + u];
      vv[u] += tv * Wv[f*32 + ob + u];
    }
  }
  #pragma unroll
  for (int u = 0; u < 8; u++){
    Sw[s*33 + ob + u] = q[u];     // Q into S region
    Kw[s*33 + ob + u] = kk[u];
    Vw[s*33 + ob + u] = vv[u];
  }
  // attention: lane -> (h = lane>>5, i = (lane>>1)&15, half = lane&1)
  const int ai = (lane >> 1) & 15;
  const int hb = (lane >> 5) * 16 + (lane & 1) * 8;
  float qreg[8];
  #pragma unroll
  for (int u = 0; u < 8; u++) qreg[u] = Sw[ai*33 + hb + u];
  float sc[16];
  float mx = -1e30f;
  #pragma unroll
  for (int j = 0; j < 16; j++){
    float d = 0.f;
    #pragma unroll
    for (int u = 0; u < 8; u++) d += qreg[u] * Kw[j*33 + hb + u];
    d += __shfl_xor(d, 1);       // combine the two halves of the dk-dot
    d *= 0.25f;
    sc[j] = d;
    mx = fmaxf(mx, d);
  }
  float den = 0.f;
  #pragma unroll
  for (int j = 0; j < 16; j++){ sc[j] = __expf(sc[j] - mx); den += sc[j]; }
  const float ainv = 1.0f / den;
  float at[8];
  #pragma unroll
  for (int u = 0; u < 8; u++) at[u] = 0.f;
  #pragma unroll
  for (int j = 0; j < 16; j++){
    float al = sc[j];
    #pragma unroll
    for (int u = 0; u < 8; u++) at[u] += al * Vw[j*33 + hb + u];
  }
  #pragma unroll
  for (int u = 0; u < 8; u++) Sw[ai*33 + hb + u] = at[u] * ainv;  // A over Q
  // out-proj + residual + LN1 (back to (s,cg))
  float xr[8];
  #pragma unroll
  for (int u = 0; u < 8; u++) xr[u] = Bo[ob + u];
  for (int i2 = 0; i2 < 32; i2++){
    float av = Sw[s*33 + i2];
    #pragma unroll
    for (int u = 0; u < 8; u++) xr[u] += av * Wo[i2*32 + ob + u];
  }
  #pragma unroll
  for (int u = 0; u < 8; u++) xr[u] += Tw[s*33 + ob + u];
  float sm = 0.f, sq = 0.f;
  #pragma unroll
  for (int u = 0; u < 8; u++){ sm += xr[u]; sq += xr[u]*xr[u]; }
  sm += __shfl_xor(sm, 1); sq += __shfl_xor(sq, 1);
  sm += __shfl_xor(sm, 2); sq += __shfl_xor(sq, 2);
  {
    float mean = sm * (1.f/32.f);
    float var  = sq * (1.f/32.f) - mean*mean;
    float rinv = 1.0f / sqrtf(var + 1e-3f);
    #pragma unroll
    for (int u = 0; u < 8; u++)
      Tw[s*33 + ob + u] = (xr[u] - mean) * rinv * L1g[ob+u] + L1b[ob+u];
  }
  // FF1 -> F2 in S (stride 66; A dead)
  {
    const int cb = cg * 16;
    #pragma unroll
    for (int t = 0; t < 16; t++){
      int c = cb + t;
      float a = Fb1[c];
      for (int f = 0; f < 32; f++) a += Tw[s*33 + f] * Fw1[f*64 + c];
      Sw[s*66 + c] = gelu_exact(a);
    }
  }
  // FF2 + residual + LN2
  float y[8];
  #pragma unroll
  for (int u = 0; u < 8; u++) y[u] = Fb2[ob + u];
  for (int c = 0; c < 64; c++){
    float fv = Sw[s*66 + c];
    #pragma unroll
    for (int u = 0; u < 8; u++) y[u] += fv * Fw2[c*32 + ob + u];
  }
  #pragma unroll
  for (int u = 0; u < 8; u++) y[u] += Tw[s*33 + ob + u];
  sm = 0.f; sq = 0.f;
  #pragma unroll
  for (int u = 0; u < 8; u++){ sm += y[u]; sq += y[u]*y[u]; }
  sm += __shfl_xor(sm, 1); sq += __shfl_xor(sq, 1);
  sm += __shfl_xor(sm, 2); sq += __shfl_xor(sq, 2);
  float mean2 = sm * (1.f/32.f);
  float var2  = sq * (1.f/32.f) - mean2*mean2;
  float rinv2 = 1.0f / sqrtf(var2 + 1e-3f);
  // mean over the 16 tokens (butterfly over s bits: 4,8,16,32)
  float mv[8];
  #pragma unroll
  for (int u = 0; u < 8; u++){
    float v = (y[u] - mean2) * rinv2 * L2g[ob+u] + L2b[ob+u];
    v += __shfl_xor(v, 4);  v += __shfl_xor(v, 8);
    v += __shfl_xor(v, 16); v += __shfl_xor(v, 32);
    mv[u] = v * (1.f/16.f);
  }
  if (s == 0){
    #pragma unroll
    for (int u = 0; u < 8; u++) Tw[ob + u] = mv[u];   // M into T row 0
  }
  // readout (t = lane&15, redundant across 4 groups)
  const int t = lane & 15;
  float hid = Rb1v[t];
  for (int o2 = 0; o2 < 32; o2++) hid += Tw[o2] * Rw1[o2*16 + t];
  hid = gelu_exact(hid) * Rw2[t];
  hid += __shfl_xor(hid, 1); hid += __shfl_xor(hid, 2);
  hid += __shfl_xor(hid, 4); hid += __shfl_xor(hid, 8);
  if (lane == 0) out[p] = hid + Rb2s[0];
}

extern "C" void kernel_launch(void* const* d_in, const int* in_sizes, int n_in,
                              void* d_out, int out_size, void* d_ws, size_t ws_size,
                              hipStream_t stream){
  const float* x    = (const float*)d_in[0];
  const float* adj  = (const float*)d_in[1];
  const float* pw   = (const float*)d_in[2];
  const float* pb   = (const float*)d_in[3];
  const float* g1w  = (const float*)d_in[4];
  const float* g1as = (const float*)d_in[5];
  const float* g1ad = (const float*)d_in[6];
  const float* g1b  = (const float*)d_in[7];
  const float* g2w  = (const float*)d_in[8];
  const float* g2as = (const float*)d_in[9];
  const float* g2ad = (const float*)d_in[10];
  const float* g2b  = (const float*)d_in[11];

  char* ws = (char*)d_ws;
  unsigned short* nlist = (unsigned short*)(ws + OFF_NBR);
  int*   cnt = (int*)(ws + OFF_CNT);
  float* hp1 = (float*)(ws + OFF_HP1);
  float* es1 = (float*)(ws + OFF_ES1);
  float* ed1 = (float*)(ws + OFF_ED1);
  float* hp2 = (float*)(ws + OFF_HP2);
  float* es2 = (float*)(ws + OFF_ES2);
  float* ed2 = (float*)(ws + OFF_ED2);

  TW tw;
  for (int t = 0; t < 20; t++) tw.p[t] = (const float*)d_in[12 + t];

  hipLaunchKernelGGL(k_nbr_pre1, dim3(NN + 100), dim3(256), 0, stream,
                     adj, x, pw, pb, g1w, g1as, g1ad, nlist, cnt, hp1, es1, ed1);
  hipLaunchKernelGGL(k_gat1pre2, dim3(100), dim3(256), 0, stream,
                     hp1, es1, ed1, nlist, cnt, g1b, g2w, g2as, g2ad, hp2, es2, ed2);
  hipLaunchKernelGGL(k_trans7, dim3(NSEQ/4), dim3(256), 0, stream,
                     hp2, es2, ed2, nlist, cnt, g2b, tw, (float*)d_out);
}

// Round 20
// 58.354 us; speedup vs baseline: 1.2399x; 1.1140x over previous
//
#include <hip/hip_runtime.h>

#define DEVINL __device__ __forceinline__

DEVINL float gelu_exact(float x){ return 0.5f * x * (1.0f + erff(x * 0.70710678118654752f)); }
DEVINL float lrelu02(float x){ return x >= 0.0f ? x : 0.2f * x; }

// B=4 S=16 N=400 -> 64 graph batches, 25600 node-rows, 1600 sequences
#define NN    400
#define NROWS 25600
#define NSEQ  1600

// ws byte offsets (all 16B-aligned, non-overlapping)
#define OFF_NBR  0u
#define OFF_CNT  320000u
#define OFF_HP1  321600u
#define OFF_ES1  1960000u
#define OFF_ED1  2369600u
#define OFF_HP2  2779200u
#define OFF_ES2  6056000u
#define OFF_ED2  6465600u

// K_A: block-split union kernel.
//   blocks [0,400):    sparse neighbor lists (one wave per row, f64 cosine)
//   blocks [400,500):  fused proj + GAT1-pre (hp1, es1, ed1), one thread/row
__global__ __launch_bounds__(256) void k_nbr_pre1(const float* __restrict__ emb,
    const float* __restrict__ x, const float* __restrict__ pw, const float* __restrict__ pb,
    const float* __restrict__ g1w, const float* __restrict__ as1, const float* __restrict__ ad1,
    unsigned short* __restrict__ nlist, int* __restrict__ cnt,
    float* __restrict__ hp1, float* __restrict__ es1, float* __restrict__ ed1){
  if (blockIdx.x < NN){
    const int i = blockIdx.x;
    const int lane = threadIdx.x;
    if (lane >= 64) return;
    double ai[16];
    double si = 0.0;
    #pragma unroll
    for (int k = 0; k < 16; k++){ ai[k] = (double)emb[i*16 + k]; si += ai[k]*ai[k]; }
    const double rni = 1.0 / sqrt(fmax(si, 1e-12));
    int base = 0;
    #pragma unroll
    for (int t = 0; t < 7; t++){
      const int j = t*64 + lane;
      bool valid = false;
      if (j < NN){
        double sj = 0.0, dp = 0.0;
        #pragma unroll
        for (int k = 0; k < 16; k++){
          double bv = (double)emb[j*16 + k];
          sj += bv*bv; dp += ai[k]*bv;
        }
        double c = dp * rni / sqrt(fmax(sj, 1e-12));
        valid = (c > 0.5);
      }
      unsigned long long bal = __ballot(valid);
      int pre = __popcll(bal & ((1ull << lane) - 1ull));
      if (valid) nlist[i*NN + base + pre] = (unsigned short)j;
      base += (int)__popcll(bal);
    }
    if (lane == 0) cnt[i] = base;
    return;
  }
  // ---- pre1 ----
  __shared__ float s_pw[48], s_pb[16], s_w[256], s_as[16], s_ad[16];
  const int tid = threadIdx.x;
  if (tid < 48) s_pw[tid] = pw[tid];
  if (tid < 16){ s_pb[tid] = pb[tid]; s_as[tid] = as1[tid]; s_ad[tid] = ad1[tid]; }
  s_w[tid] = g1w[tid];
  __syncthreads();
  const int row = (blockIdx.x - NN) * 256 + tid;
  if (row >= NROWS) return;
  float x0 = x[row*3+0], x1v = x[row*3+1], x2 = x[row*3+2];
  float h0[16];
  #pragma unroll
  for (int c = 0; c < 16; c++)
    h0[c] = s_pb[c] + x0 * s_pw[c] + x1v * s_pw[16+c] + x2 * s_pw[32+c];
  float hp[16];
  #pragma unroll
  for (int c = 0; c < 16; c++){
    float a = 0.f;
    #pragma unroll
    for (int k = 0; k < 16; k++) a += h0[k] * s_w[k*16 + c];
    hp[c] = a;
  }
  float4* hout = (float4*)(hp1 + (size_t)row * 16);
  hout[0] = make_float4(hp[0],hp[1],hp[2],hp[3]);
  hout[1] = make_float4(hp[4],hp[5],hp[6],hp[7]);
  hout[2] = make_float4(hp[8],hp[9],hp[10],hp[11]);
  hout[3] = make_float4(hp[12],hp[13],hp[14],hp[15]);
  #pragma unroll
  for (int h = 0; h < 4; h++){
    float es = 0.f, ed = 0.f;
    #pragma unroll
    for (int d = 0; d < 4; d++){ es += hp[h*4+d]*s_as[h*4+d]; ed += hp[h*4+d]*s_ad[h*4+d]; }
    es1[row*4 + h] = es;
    ed1[row*4 + h] = ed;
  }
}

// K_B v2: fused GAT1 + gelu + pre2, ONE THREAD PER (row, head).
// 4x parallelism vs one-thread-per-row: 102400 threads = 1600 waves.
// Lanes of a row are adjacent (row = tid>>2, h = tid&3) -> coalesced gathers.
// x1 exchanged across the row's 4 lanes via LDS; per-head summation order
// identical to the previous version (chunk-8 ascending) -> bit-identical.
__global__ __launch_bounds__(256) void k_gat1pre2(
    const float* __restrict__ hp1, const float* __restrict__ es1, const float* __restrict__ ed1,
    const unsigned short* __restrict__ nlist, const int* __restrict__ cnt,
    const float* __restrict__ g1b, const float* __restrict__ g2w,
    const float* __restrict__ as2, const float* __restrict__ ad2,
    float* __restrict__ hp2, float* __restrict__ es2, float* __restrict__ ed2){
  __shared__ float s_w[512], s_b1[16], s_as[32], s_ad[32];
  __shared__ float x1s[64][17];            // 64 rows per block, +1 pad
  const int tid = threadIdx.x;
  s_w[tid] = g2w[tid]; s_w[tid+256] = g2w[tid+256];
  if (tid < 16) s_b1[tid] = g1b[tid];
  if (tid < 32){ s_as[tid] = as2[tid]; s_ad[tid] = ad2[tid]; }
  __syncthreads();
  const int lrow = tid >> 2, h = tid & 3;
  const int row = blockIdx.x * 64 + lrow;
  const int gb = row / NN;
  const int i  = row - gb * NN;
  const int n  = cnt[i];
  const unsigned short* nl = nlist + i * NN;
  const int rbase = gb * NN;
  const float edh = ed1[(size_t)row * 4 + h];
  // pass 1: masked max of es (per head)
  float mx = -1e30f;
  for (int k0 = 0; k0 < n; k0 += 8){
    int jj[8]; float wv[8];
    #pragma unroll
    for (int u = 0; u < 8; u++){
      int kk = k0+u; jj[u] = (int)nl[kk < n ? kk : n-1]; wv[u] = (kk < n) ? 1.f : 0.f;
    }
    #pragma unroll
    for (int u = 0; u < 8; u++){
      float v = es1[(size_t)(rbase + jj[u]) * 4 + h];
      mx = fmaxf(mx, wv[u] > 0.5f ? v : -1e30f);
    }
  }
  const float m = lrelu02(edh + mx);
  // pass 2: denom + weighted accumulate (4-dim head slice)
  float den = 0.f;
  float acc[4] = {0.f, 0.f, 0.f, 0.f};
  for (int k0 = 0; k0 < n; k0 += 8){
    int jj[8]; float wv[8], ev[8];
    #pragma unroll
    for (int u = 0; u < 8; u++){
      int kk = k0+u; jj[u] = (int)nl[kk < n ? kk : n-1]; wv[u] = (kk < n) ? 1.f : 0.f;
    }
    #pragma unroll
    for (int u = 0; u < 8; u++) ev[u] = es1[(size_t)(rbase + jj[u]) * 4 + h];
    #pragma unroll
    for (int u = 0; u < 8; u++){
      float pv = wv[u] * __expf(lrelu02(edh + ev[u]) - m);
      den += pv;
      float4 hv = *(const float4*)(hp1 + (size_t)(rbase + jj[u]) * 16 + h * 4);
      acc[0] += pv*hv.x; acc[1] += pv*hv.y; acc[2] += pv*hv.z; acc[3] += pv*hv.w;
    }
  }
  const float inv = 1.0f / den;
  #pragma unroll
  for (int d = 0; d < 4; d++)
    x1s[lrow][h*4 + d] = gelu_exact(acc[d] * inv + s_b1[h*4 + d]);
  __syncthreads();
  // pre2: thread h computes hp2 columns [h*8, h*8+8) of its row + es2/ed2 for head h
  float xr[16];
  #pragma unroll
  for (int k = 0; k < 16; k++) xr[k] = x1s[lrow][k];
  const int cb = h * 8;
  float hp[8];
  #pragma unroll
  for (int c = 0; c < 8; c++){
    float a = 0.f;
    #pragma unroll
    for (int k = 0; k < 16; k++) a += xr[k] * s_w[k*32 + cb + c];
    hp[c] = a;
  }
  float4* ho = (float4*)(hp2 + (size_t)row * 32 + cb);
  ho[0] = make_float4(hp[0], hp[1], hp[2], hp[3]);
  ho[1] = make_float4(hp[4], hp[5], hp[6], hp[7]);
  float es = 0.f, ed = 0.f;
  #pragma unroll
  for (int d = 0; d < 8; d++){ es += hp[d]*s_as[cb+d]; ed += hp[d]*s_ad[cb+d]; }
  es2[(size_t)row*4 + h] = es;
  ed2[(size_t)row*4 + h] = ed;
}

struct TW { const float* p[20]; };
// order: 0 wq,1 bq,2 wk,3 bk,4 wv,5 bv,6 wo,7 bo,8 ln1g,9 ln1b,
//        10 fw1,11 fb1,12 fw2,13 fb2,14 ln2g,15 ln2b,16 rw1,17 rb1,18 rw2,19 rb2

// K_D v7b (round-17/19 measured best): trans3 + FUSED sparse GAT2 with correct
// reshape mapping: token s of sequence p is h2 flat row r = p*16+s;
// that row's graph-batch gb = r/400, node i = r%400 (per-LANE).
__global__ __launch_bounds__(256) void k_trans7(
    const float* __restrict__ hp2, const float* __restrict__ es2,
    const float* __restrict__ ed2, const unsigned short* __restrict__ nlist,
    const int* __restrict__ cnt, const float* __restrict__ g2b,
    TW tw, float* __restrict__ out){
  __shared__ float Wq[1024], Wk[1024], Wv[1024], Wo[1024];
  __shared__ float Fw1[2048], Fw2[2048], Rw1[512];
  __shared__ float Bq[32], Bk[32], Bv[32], Bo[32], L1g[32], L1b[32];
  __shared__ float Fb1[64], Fb2[32], L2g[32], L2b[32], Rb1v[16], Rw2[16];
  __shared__ float Gb2[32];
  __shared__ float Rb2s[1];
  __shared__ float SCR[4][2640];   // per-wave: T 528 | K 528 | V 528 | S 1056
  const int tid = threadIdx.x;
  const int w = tid >> 6, lane = tid & 63;
  for (int i = tid; i < 1024; i += 256){
    Wq[i] = tw.p[0][i]; Wk[i] = tw.p[2][i]; Wv[i] = tw.p[4][i]; Wo[i] = tw.p[6][i];
  }
  for (int i = tid; i < 2048; i += 256){ Fw1[i] = tw.p[10][i]; Fw2[i] = tw.p[12][i]; }
  for (int i = tid; i < 512; i += 256) Rw1[i] = tw.p[16][i];
  if (tid < 32){
    Bq[tid] = tw.p[1][tid]; Bk[tid] = tw.p[3][tid]; Bv[tid] = tw.p[5][tid]; Bo[tid] = tw.p[7][tid];
    L1g[tid] = tw.p[8][tid]; L1b[tid] = tw.p[9][tid]; Fb2[tid] = tw.p[13][tid];
    L2g[tid] = tw.p[14][tid]; L2b[tid] = tw.p[15][tid];
    Gb2[tid] = g2b[tid];
  }
  if (tid < 64) Fb1[tid] = tw.p[11][tid];
  if (tid < 16){ Rb1v[tid] = tw.p[17][tid]; Rw2[tid] = tw.p[18][tid]; }
  if (tid == 0) Rb2s[0] = tw.p[19][0];
  __syncthreads();   // the only block barrier

  float* Tw = SCR[w];
  float* Kw = Tw + 528;
  float* Vw = Tw + 1056;
  float* Sw = Tw + 1584;
  const int p = blockIdx.x * 4 + w;
  const int s = lane >> 2, cg = lane & 3, ob = cg * 8;

  // ---- fused GAT2: lane (s, h=cg) computes T[s][ob..ob+8) for h2-row r=p*16+s ----
  {
    const int r  = p * 16 + s;
    const int gb = r / NN;               // graph batch of this row
    const int i  = r - gb * NN;          // node id of this row
    const int n  = cnt[i];
    const unsigned short* nl = nlist + i * NN;
    const int rbase = gb * NN;
    const float edh = ed2[(size_t)r * 4 + cg];
    float mx = -1e30f;
    for (int k0 = 0; k0 < n; k0 += 8){
      int jj[8]; float wv[8];
      #pragma unroll
      for (int u = 0; u < 8; u++){
        int kk = k0+u; jj[u] = (int)nl[kk < n ? kk : n-1]; wv[u] = (kk < n) ? 1.f : 0.f;
      }
      #pragma unroll
      for (int u = 0; u < 8; u++){
        float v = es2[(size_t)(rbase + jj[u]) * 4 + cg];
        mx = fmaxf(mx, wv[u] > 0.5f ? v : -1e30f);
      }
    }
    const float m = lrelu02(edh + mx);
    float den = 0.f;
    float acc[8];
    #pragma unroll
    for (int d = 0; d < 8; d++) acc[d] = 0.f;
    for (int k0 = 0; k0 < n; k0 += 8){
      int jj[8]; float wv[8], ev[8];
      #pragma unroll
      for (int u = 0; u < 8; u++){
        int kk = k0+u; jj[u] = (int)nl[kk < n ? kk : n-1]; wv[u] = (kk < n) ? 1.f : 0.f;
      }
      #pragma unroll
      for (int u = 0; u < 8; u++) ev[u] = es2[(size_t)(rbase + jj[u]) * 4 + cg];
      #pragma unroll
      for (int u = 0; u < 8; u++){
        float pv = wv[u] * __expf(lrelu02(edh + ev[u]) - m);
        den += pv;
        const float4* vp = (const float4*)(hp2 + (size_t)(rbase + jj[u]) * 32 + cg * 8);
        float4 v0 = vp[0], v1 = vp[1];
        acc[0] += pv*v0.x; acc[1] += pv*v0.y; acc[2] += pv*v0.z; acc[3] += pv*v0.w;
        acc[4] += pv*v1.x; acc[5] += pv*v1.y; acc[6] += pv*v1.z; acc[7] += pv*v1.w;
      }
    }
    const float invd = 1.0f / den;
    float* tr = Tw + s*33 + ob;
    #pragma unroll
    for (int u = 0; u < 8; u++) tr[u] = acc[u] * invd + Gb2[ob + u];
  }
  // ---- transformer (verbatim trans3 from here) ----
  float q[8], kk[8], vv[8];
  #pragma unroll
  for (int u = 0; u < 8; u++){ q[u] = Bq[ob+u]; kk[u] = Bk[ob+u]; vv[u] = Bv[ob+u]; }
  for (int f = 0; f < 32; f++){
    float tv = Tw[s*33 + f];
    #pragma unroll
    for (int u = 0; u < 8; u++){
      q[u]  += tv * Wq[f*32 + ob + u];
      kk[u] += tv * Wk[f*32 + ob + u];
      vv[u] += tv * Wv[f*32 + ob + u];
    }
  }
  #pragma unroll
  for (int u = 0; u < 8; u++){
    Sw[s*33 + ob + u] = q[u];     // Q into S region
    Kw[s*33 + ob + u] = kk[u];
    Vw[s*33 + ob + u] = vv[u];
  }
  // attention: lane -> (h = lane>>5, i = (lane>>1)&15, half = lane&1)
  const int ai = (lane >> 1) & 15;
  const int hb = (lane >> 5) * 16 + (lane & 1) * 8;
  float qreg[8];
  #pragma unroll
  for (int u = 0; u < 8; u++) qreg[u] = Sw[ai*33 + hb + u];
  float sc[16];
  float mx = -1e30f;
  #pragma unroll
  for (int j = 0; j < 16; j++){
    float d = 0.f;
    #pragma unroll
    for (int u = 0; u < 8; u++) d += qreg[u] * Kw[j*33 + hb + u];
    d += __shfl_xor(d, 1);       // combine the two halves of the dk-dot
    d *= 0.25f;
    sc[j] = d;
    mx = fmaxf(mx, d);
  }
  float den = 0.f;
  #pragma unroll
  for (int j = 0; j < 16; j++){ sc[j] = __expf(sc[j] - mx); den += sc[j]; }
  const float ainv = 1.0f / den;
  float at[8];
  #pragma unroll
  for (int u = 0; u < 8; u++) at[u] = 0.f;
  #pragma unroll
  for (int j = 0; j < 16; j++){
    float al = sc[j];
    #pragma unroll
    for (int u = 0; u < 8; u++) at[u] += al * Vw[j*33 + hb + u];
  }
  #pragma unroll
  for (int u = 0; u < 8; u++) Sw[ai*33 + hb + u] = at[u] * ainv;  // A over Q
  // out-proj + residual + LN1 (back to (s,cg))
  float xr[8];
  #pragma unroll
  for (int u = 0; u < 8; u++) xr[u] = Bo[ob + u];
  for (int i2 = 0; i2 < 32; i2++){
    float av = Sw[s*33 + i2];
    #pragma unroll
    for (int u = 0; u < 8; u++) xr[u] += av * Wo[i2*32 + ob + u];
  }
  #pragma unroll
  for (int u = 0; u < 8; u++) xr[u] += Tw[s*33 + ob + u];
  float sm = 0.f, sq = 0.f;
  #pragma unroll
  for (int u = 0; u < 8; u++){ sm += xr[u]; sq += xr[u]*xr[u]; }
  sm += __shfl_xor(sm, 1); sq += __shfl_xor(sq, 1);
  sm += __shfl_xor(sm, 2); sq += __shfl_xor(sq, 2);
  {
    float mean = sm * (1.f/32.f);
    float var  = sq * (1.f/32.f) - mean*mean;
    float rinv = 1.0f / sqrtf(var + 1e-3f);
    #pragma unroll
    for (int u = 0; u < 8; u++)
      Tw[s*33 + ob + u] = (xr[u] - mean) * rinv * L1g[ob+u] + L1b[ob+u];
  }
  // FF1 -> F2 in S (stride 66; A dead)
  {
    const int cb = cg * 16;
    #pragma unroll
    for (int t = 0; t < 16; t++){
      int c = cb + t;
      float a = Fb1[c];
      for (int f = 0; f < 32; f++) a += Tw[s*33 + f] * Fw1[f*64 + c];
      Sw[s*66 + c] = gelu_exact(a);
    }
  }
  // FF2 + residual + LN2
  float y[8];
  #pragma unroll
  for (int u = 0; u < 8; u++) y[u] = Fb2[ob + u];
  for (int c = 0; c < 64; c++){
    float fv = Sw[s*66 + c];
    #pragma unroll
    for (int u = 0; u < 8; u++) y[u] += fv * Fw2[c*32 + ob + u];
  }
  #pragma unroll
  for (int u = 0; u < 8; u++) y[u] += Tw[s*33 + ob + u];
  sm = 0.f; sq = 0.f;
  #pragma unroll
  for (int u = 0; u < 8; u++){ sm += y[u]; sq += y[u]*y[u]; }
  sm += __shfl_xor(sm, 1); sq += __shfl_xor(sq, 1);
  sm += __shfl_xor(sm, 2); sq += __shfl_xor(sq, 2);
  float mean2 = sm * (1.f/32.f);
  float var2  = sq * (1.f/32.f) - mean2*mean2;
  float rinv2 = 1.0f / sqrtf(var2 + 1e-3f);
  // mean over the 16 tokens (butterfly over s bits: 4,8,16,32)
  float mv[8];
  #pragma unroll
  for (int u = 0; u < 8; u++){
    float v = (y[u] - mean2) * rinv2 * L2g[ob+u] + L2b[ob+u];
    v += __shfl_xor(v, 4);  v += __shfl_xor(v, 8);
    v += __shfl_xor(v, 16); v += __shfl_xor(v, 32);
    mv[u] = v * (1.f/16.f);
  }
  if (s == 0){
    #pragma unroll
    for (int u = 0; u < 8; u++) Tw[ob + u] = mv[u];   // M into T row 0
  }
  // readout (t = lane&15, redundant across 4 groups)
  const int t = lane & 15;
  float hid = Rb1v[t];
  for (int o2 = 0; o2 < 32; o2++) hid += Tw[o2] * Rw1[o2*16 + t];
  hid = gelu_exact(hid) * Rw2[t];
  hid += __shfl_xor(hid, 1); hid += __shfl_xor(hid, 2);
  hid += __shfl_xor(hid, 4); hid += __shfl_xor(hid, 8);
  if (lane == 0) out[p] = hid + Rb2s[0];
}

extern "C" void kernel_launch(void* const* d_in, const int* in_sizes, int n_in,
                              void* d_out, int out_size, void* d_ws, size_t ws_size,
                              hipStream_t stream){
  const float* x    = (const float*)d_in[0];
  const float* adj  = (const float*)d_in[1];
  const float* pw   = (const float*)d_in[2];
  const float* pb   = (const float*)d_in[3];
  const float* g1w  = (const float*)d_in[4];
  const float* g1as = (const float*)d_in[5];
  const float* g1ad = (const float*)d_in[6];
  const float* g1b  = (const float*)d_in[7];
  const float* g2w  = (const float*)d_in[8];
  const float* g2as = (const float*)d_in[9];
  const float* g2ad = (const float*)d_in[10];
  const float* g2b  = (const float*)d_in[11];

  char* ws = (char*)d_ws;
  unsigned short* nlist = (unsigned short*)(ws + OFF_NBR);
  int*   cnt = (int*)(ws + OFF_CNT);
  float* hp1 = (float*)(ws + OFF_HP1);
  float* es1 = (float*)(ws + OFF_ES1);
  float* ed1 = (float*)(ws + OFF_ED1);
  float* hp2 = (float*)(ws + OFF_HP2);
  float* es2 = (float*)(ws + OFF_ES2);
  float* ed2 = (float*)(ws + OFF_ED2);

  TW tw;
  for (int t = 0; t < 20; t++) tw.p[t] = (const float*)d_in[12 + t];

  hipLaunchKernelGGL(k_nbr_pre1, dim3(NN + 100), dim3(256), 0, stream,
                     adj, x, pw, pb, g1w, g1as, g1ad, nlist, cnt, hp1, es1, ed1);
  hipLaunchKernelGGL(k_gat1pre2, dim3(NROWS/64), dim3(256), 0, stream,
                     hp1, es1, ed1, nlist, cnt, g1b, g2w, g2as, g2ad, hp2, es2, ed2);
  hipLaunchKernelGGL(k_trans7, dim3(NSEQ/4), dim3(256), 0, stream,
                     hp2, es2, ed2, nlist, cnt, g2b, tw, (float*)d_out);
}

// Round 21
// 58.299 us; speedup vs baseline: 1.2411x; 1.0009x over previous
//
#include <hip/hip_runtime.h>

#define DEVINL __device__ __forceinline__

DEVINL float gelu_exact(float x){ return 0.5f * x * (1.0f + erff(x * 0.70710678118654752f)); }
DEVINL float lrelu02(float x){ return x >= 0.0f ? x : 0.2f * x; }

// B=4 S=16 N=400 -> 64 graph batches, 25600 node-rows, 1600 sequences
#define NN    400
#define NROWS 25600
#define NSEQ  1600

// ws byte offsets (all 16B-aligned, non-overlapping)
#define OFF_NBR  0u
#define OFF_CNT  320000u
#define OFF_HP1  321600u
#define OFF_ES1  1960000u
#define OFF_ED1  2369600u
#define OFF_HP2  2779200u
#define OFF_ES2  6056000u
#define OFF_ED2  6465600u

// K_A: block-split union kernel.
//   blocks [0,100):    sparse neighbor lists, 4 ROWS PER BLOCK (one wave per row)
//   blocks [100,200):  fused proj + GAT1-pre (hp1, es1, ed1), one thread/row
__global__ __launch_bounds__(256) void k_nbr_pre1(const float* __restrict__ emb,
    const float* __restrict__ x, const float* __restrict__ pw, const float* __restrict__ pb,
    const float* __restrict__ g1w, const float* __restrict__ as1, const float* __restrict__ ad1,
    unsigned short* __restrict__ nlist, int* __restrict__ cnt,
    float* __restrict__ hp1, float* __restrict__ es1, float* __restrict__ ed1){
  if (blockIdx.x < NN/4){
    const int i = blockIdx.x * 4 + (threadIdx.x >> 6);   // wave -> row
    const int lane = threadIdx.x & 63;
    double ai[16];
    double si = 0.0;
    #pragma unroll
    for (int k = 0; k < 16; k++){ ai[k] = (double)emb[i*16 + k]; si += ai[k]*ai[k]; }
    const double rni = 1.0 / sqrt(fmax(si, 1e-12));
    int base = 0;
    #pragma unroll
    for (int t = 0; t < 7; t++){
      const int j = t*64 + lane;
      bool valid = false;
      if (j < NN){
        double sj = 0.0, dp = 0.0;
        #pragma unroll
        for (int k = 0; k < 16; k++){
          double bv = (double)emb[j*16 + k];
          sj += bv*bv; dp += ai[k]*bv;
        }
        double c = dp * rni / sqrt(fmax(sj, 1e-12));
        valid = (c > 0.5);
      }
      unsigned long long bal = __ballot(valid);
      int pre = __popcll(bal & ((1ull << lane) - 1ull));
      if (valid) nlist[i*NN + base + pre] = (unsigned short)j;
      base += (int)__popcll(bal);
    }
    if (lane == 0) cnt[i] = base;
    return;
  }
  // ---- pre1 ----
  __shared__ float s_pw[48], s_pb[16], s_w[256], s_as[16], s_ad[16];
  const int tid = threadIdx.x;
  if (tid < 48) s_pw[tid] = pw[tid];
  if (tid < 16){ s_pb[tid] = pb[tid]; s_as[tid] = as1[tid]; s_ad[tid] = ad1[tid]; }
  s_w[tid] = g1w[tid];
  __syncthreads();
  const int row = (blockIdx.x - NN/4) * 256 + tid;
  if (row >= NROWS) return;
  float x0 = x[row*3+0], x1v = x[row*3+1], x2 = x[row*3+2];
  float h0[16];
  #pragma unroll
  for (int c = 0; c < 16; c++)
    h0[c] = s_pb[c] + x0 * s_pw[c] + x1v * s_pw[16+c] + x2 * s_pw[32+c];
  float hp[16];
  #pragma unroll
  for (int c = 0; c < 16; c++){
    float a = 0.f;
    #pragma unroll
    for (int k = 0; k < 16; k++) a += h0[k] * s_w[k*16 + c];
    hp[c] = a;
  }
  float4* hout = (float4*)(hp1 + (size_t)row * 16);
  hout[0] = make_float4(hp[0],hp[1],hp[2],hp[3]);
  hout[1] = make_float4(hp[4],hp[5],hp[6],hp[7]);
  hout[2] = make_float4(hp[8],hp[9],hp[10],hp[11]);
  hout[3] = make_float4(hp[12],hp[13],hp[14],hp[15]);
  #pragma unroll
  for (int h = 0; h < 4; h++){
    float es = 0.f, ed = 0.f;
    #pragma unroll
    for (int d = 0; d < 4; d++){ es += hp[h*4+d]*s_as[h*4+d]; ed += hp[h*4+d]*s_ad[h*4+d]; }
    es1[row*4 + h] = es;
    ed1[row*4 + h] = ed;
  }
}

// K_B v2: fused GAT1 + gelu + pre2, ONE THREAD PER (row, head).
__global__ __launch_bounds__(256) void k_gat1pre2(
    const float* __restrict__ hp1, const float* __restrict__ es1, const float* __restrict__ ed1,
    const unsigned short* __restrict__ nlist, const int* __restrict__ cnt,
    const float* __restrict__ g1b, const float* __restrict__ g2w,
    const float* __restrict__ as2, const float* __restrict__ ad2,
    float* __restrict__ hp2, float* __restrict__ es2, float* __restrict__ ed2){
  __shared__ float s_w[512], s_b1[16], s_as[32], s_ad[32];
  __shared__ float x1s[64][17];            // 64 rows per block, +1 pad
  const int tid = threadIdx.x;
  s_w[tid] = g2w[tid]; s_w[tid+256] = g2w[tid+256];
  if (tid < 16) s_b1[tid] = g1b[tid];
  if (tid < 32){ s_as[tid] = as2[tid]; s_ad[tid] = ad2[tid]; }
  __syncthreads();
  const int lrow = tid >> 2, h = tid & 3;
  const int row = blockIdx.x * 64 + lrow;
  const int gb = row / NN;
  const int i  = row - gb * NN;
  const int n  = cnt[i];
  const unsigned short* nl = nlist + i * NN;
  const int rbase = gb * NN;
  const float edh = ed1[(size_t)row * 4 + h];
  float mx = -1e30f;
  for (int k0 = 0; k0 < n; k0 += 8){
    int jj[8]; float wv[8];
    #pragma unroll
    for (int u = 0; u < 8; u++){
      int kk = k0+u; jj[u] = (int)nl[kk < n ? kk : n-1]; wv[u] = (kk < n) ? 1.f : 0.f;
    }
    #pragma unroll
    for (int u = 0; u < 8; u++){
      float v = es1[(size_t)(rbase + jj[u]) * 4 + h];
      mx = fmaxf(mx, wv[u] > 0.5f ? v : -1e30f);
    }
  }
  const float m = lrelu02(edh + mx);
  float den = 0.f;
  float acc[4] = {0.f, 0.f, 0.f, 0.f};
  for (int k0 = 0; k0 < n; k0 += 8){
    int jj[8]; float wv[8], ev[8];
    #pragma unroll
    for (int u = 0; u < 8; u++){
      int kk = k0+u; jj[u] = (int)nl[kk < n ? kk : n-1]; wv[u] = (kk < n) ? 1.f : 0.f;
    }
    #pragma unroll
    for (int u = 0; u < 8; u++) ev[u] = es1[(size_t)(rbase + jj[u]) * 4 + h];
    #pragma unroll
    for (int u = 0; u < 8; u++){
      float pv = wv[u] * __expf(lrelu02(edh + ev[u]) - m);
      den += pv;
      float4 hv = *(const float4*)(hp1 + (size_t)(rbase + jj[u]) * 16 + h * 4);
      acc[0] += pv*hv.x; acc[1] += pv*hv.y; acc[2] += pv*hv.z; acc[3] += pv*hv.w;
    }
  }
  const float inv = 1.0f / den;
  #pragma unroll
  for (int d = 0; d < 4; d++)
    x1s[lrow][h*4 + d] = gelu_exact(acc[d] * inv + s_b1[h*4 + d]);
  __syncthreads();
  float xr[16];
  #pragma unroll
  for (int k = 0; k < 16; k++) xr[k] = x1s[lrow][k];
  const int cb = h * 8;
  float hp[8];
  #pragma unroll
  for (int c = 0; c < 8; c++){
    float a = 0.f;
    #pragma unroll
    for (int k = 0; k < 16; k++) a += xr[k] * s_w[k*32 + cb + c];
    hp[c] = a;
  }
  float4* ho = (float4*)(hp2 + (size_t)row * 32 + cb);
  ho[0] = make_float4(hp[0], hp[1], hp[2], hp[3]);
  ho[1] = make_float4(hp[4], hp[5], hp[6], hp[7]);
  float es = 0.f, ed = 0.f;
  #pragma unroll
  for (int d = 0; d < 8; d++){ es += hp[d]*s_as[cb+d]; ed += hp[d]*s_ad[cb+d]; }
  es2[(size_t)row*4 + h] = es;
  ed2[(size_t)row*4 + h] = ed;
}

struct TW { const float* p[20]; };
// order: 0 wq,1 bq,2 wk,3 bk,4 wv,5 bv,6 wo,7 bo,8 ln1g,9 ln1b,
//        10 fw1,11 fb1,12 fw2,13 fb2,14 ln2g,15 ln2b,16 rw1,17 rb1,18 rw2,19 rb2

// K_D v7b (measured best): trans3 + FUSED sparse GAT2, correct reshape mapping.
__global__ __launch_bounds__(256) void k_trans7(
    const float* __restrict__ hp2, const float* __restrict__ es2,
    const float* __restrict__ ed2, const unsigned short* __restrict__ nlist,
    const int* __restrict__ cnt, const float* __restrict__ g2b,
    TW tw, float* __restrict__ out){
  __shared__ float Wq[1024], Wk[1024], Wv[1024], Wo[1024];
  __shared__ float Fw1[2048], Fw2[2048], Rw1[512];
  __shared__ float Bq[32], Bk[32], Bv[32], Bo[32], L1g[32], L1b[32];
  __shared__ float Fb1[64], Fb2[32], L2g[32], L2b[32], Rb1v[16], Rw2[16];
  __shared__ float Gb2[32];
  __shared__ float Rb2s[1];
  __shared__ float SCR[4][2640];   // per-wave: T 528 | K 528 | V 528 | S 1056
  const int tid = threadIdx.x;
  const int w = tid >> 6, lane = tid & 63;
  for (int i = tid; i < 1024; i += 256){
    Wq[i] = tw.p[0][i]; Wk[i] = tw.p[2][i]; Wv[i] = tw.p[4][i]; Wo[i] = tw.p[6][i];
  }
  for (int i = tid; i < 2048; i += 256){ Fw1[i] = tw.p[10][i]; Fw2[i] = tw.p[12][i]; }
  for (int i = tid; i < 512; i += 256) Rw1[i] = tw.p[16][i];
  if (tid < 32){
    Bq[tid] = tw.p[1][tid]; Bk[tid] = tw.p[3][tid]; Bv[tid] = tw.p[5][tid]; Bo[tid] = tw.p[7][tid];
    L1g[tid] = tw.p[8][tid]; L1b[tid] = tw.p[9][tid]; Fb2[tid] = tw.p[13][tid];
    L2g[tid] = tw.p[14][tid]; L2b[tid] = tw.p[15][tid];
    Gb2[tid] = g2b[tid];
  }
  if (tid < 64) Fb1[tid] = tw.p[11][tid];
  if (tid < 16){ Rb1v[tid] = tw.p[17][tid]; Rw2[tid] = tw.p[18][tid]; }
  if (tid == 0) Rb2s[0] = tw.p[19][0];
  __syncthreads();   // the only block barrier

  float* Tw = SCR[w];
  float* Kw = Tw + 528;
  float* Vw = Tw + 1056;
  float* Sw = Tw + 1584;
  const int p = blockIdx.x * 4 + w;
  const int s = lane >> 2, cg = lane & 3, ob = cg * 8;

  // ---- fused GAT2: lane (s, h=cg) computes T[s][ob..ob+8) for h2-row r=p*16+s ----
  {
    const int r  = p * 16 + s;
    const int gb = r / NN;
    const int i  = r - gb * NN;
    const int n  = cnt[i];
    const unsigned short* nl = nlist + i * NN;
    const int rbase = gb * NN;
    const float edh = ed2[(size_t)r * 4 + cg];
    float mx = -1e30f;
    for (int k0 = 0; k0 < n; k0 += 8){
      int jj[8]; float wv[8];
      #pragma unroll
      for (int u = 0; u < 8; u++){
        int kk = k0+u; jj[u] = (int)nl[kk < n ? kk : n-1]; wv[u] = (kk < n) ? 1.f : 0.f;
      }
      #pragma unroll
      for (int u = 0; u < 8; u++){
        float v = es2[(size_t)(rbase + jj[u]) * 4 + cg];
        mx = fmaxf(mx, wv[u] > 0.5f ? v : -1e30f);
      }
    }
    const float m = lrelu02(edh + mx);
    float den = 0.f;
    float acc[8];
    #pragma unroll
    for (int d = 0; d < 8; d++) acc[d] = 0.f;
    for (int k0 = 0; k0 < n; k0 += 8){
      int jj[8]; float wv[8], ev[8];
      #pragma unroll
      for (int u = 0; u < 8; u++){
        int kk = k0+u; jj[u] = (int)nl[kk < n ? kk : n-1]; wv[u] = (kk < n) ? 1.f : 0.f;
      }
      #pragma unroll
      for (int u = 0; u < 8; u++) ev[u] = es2[(size_t)(rbase + jj[u]) * 4 + cg];
      #pragma unroll
      for (int u = 0; u < 8; u++){
        float pv = wv[u] * __expf(lrelu02(edh + ev[u]) - m);
        den += pv;
        const float4* vp = (const float4*)(hp2 + (size_t)(rbase + jj[u]) * 32 + cg * 8);
        float4 v0 = vp[0], v1 = vp[1];
        acc[0] += pv*v0.x; acc[1] += pv*v0.y; acc[2] += pv*v0.z; acc[3] += pv*v0.w;
        acc[4] += pv*v1.x; acc[5] += pv*v1.y; acc[6] += pv*v1.z; acc[7] += pv*v1.w;
      }
    }
    const float invd = 1.0f / den;
    float* tr = Tw + s*33 + ob;
    #pragma unroll
    for (int u = 0; u < 8; u++) tr[u] = acc[u] * invd + Gb2[ob + u];
  }
  // ---- transformer (verbatim trans3) ----
  float q[8], kk[8], vv[8];
  #pragma unroll
  for (int u = 0; u < 8; u++){ q[u] = Bq[ob+u]; kk[u] = Bk[ob+u]; vv[u] = Bv[ob+u]; }
  for (int f = 0; f < 32; f++){
    float tv = Tw[s*33 + f];
    #pragma unroll
    for (int u = 0; u < 8; u++){
      q[u]  += tv * Wq[f*32 + ob + u];
      kk[u] += tv * Wk[f*32 + ob + u];
      vv[u] += tv * Wv[f*32 + ob + u];
    }
  }
  #pragma unroll
  for (int u = 0; u < 8; u++){
    Sw[s*33 + ob + u] = q[u];
    Kw[s*33 + ob + u] = kk[u];
    Vw[s*33 + ob + u] = vv[u];
  }
  const int ai = (lane >> 1) & 15;
  const int hb = (lane >> 5) * 16 + (lane & 1) * 8;
  float qreg[8];
  #pragma unroll
  for (int u = 0; u < 8; u++) qreg[u] = Sw[ai*33 + hb + u];
  float sc[16];
  float mx = -1e30f;
  #pragma unroll
  for (int j = 0; j < 16; j++){
    float d = 0.f;
    #pragma unroll
    for (int u = 0; u < 8; u++) d += qreg[u] * Kw[j*33 + hb + u];
    d += __shfl_xor(d, 1);
    d *= 0.25f;
    sc[j] = d;
    mx = fmaxf(mx, d);
  }
  float den = 0.f;
  #pragma unroll
  for (int j = 0; j < 16; j++){ sc[j] = __expf(sc[j] - mx); den += sc[j]; }
  const float ainv = 1.0f / den;
  float at[8];
  #pragma unroll
  for (int u = 0; u < 8; u++) at[u] = 0.f;
  #pragma unroll
  for (int j = 0; j < 16; j++){
    float al = sc[j];
    #pragma unroll
    for (int u = 0; u < 8; u++) at[u] += al * Vw[j*33 + hb + u];
  }
  #pragma unroll
  for (int u = 0; u < 8; u++) Sw[ai*33 + hb + u] = at[u] * ainv;
  float xr[8];
  #pragma unroll
  for (int u = 0; u < 8; u++) xr[u] = Bo[ob + u];
  for (int i2 = 0; i2 < 32; i2++){
    float av = Sw[s*33 + i2];
    #pragma unroll
    for (int u = 0; u < 8; u++) xr[u] += av * Wo[i2*32 + ob + u];
  }
  #pragma unroll
  for (int u = 0; u < 8; u++) xr[u] += Tw[s*33 + ob + u];
  float sm = 0.f, sq = 0.f;
  #pragma unroll
  for (int u = 0; u < 8; u++){ sm += xr[u]; sq += xr[u]*xr[u]; }
  sm += __shfl_xor(sm, 1); sq += __shfl_xor(sq, 1);
  sm += __shfl_xor(sm, 2); sq += __shfl_xor(sq, 2);
  {
    float mean = sm * (1.f/32.f);
    float var  = sq * (1.f/32.f) - mean*mean;
    float rinv = 1.0f / sqrtf(var + 1e-3f);
    #pragma unroll
    for (int u = 0; u < 8; u++)
      Tw[s*33 + ob + u] = (xr[u] - mean) * rinv * L1g[ob+u] + L1b[ob+u];
  }
  {
    const int cb = cg * 16;
    #pragma unroll
    for (int t = 0; t < 16; t++){
      int c = cb + t;
      float a = Fb1[c];
      for (int f = 0; f < 32; f++) a += Tw[s*33 + f] * Fw1[f*64 + c];
      Sw[s*66 + c] = gelu_exact(a);
    }
  }
  float y[8];
  #pragma unroll
  for (int u = 0; u < 8; u++) y[u] = Fb2[ob + u];
  for (int c = 0; c < 64; c++){
    float fv = Sw[s*66 + c];
    #pragma unroll
    for (int u = 0; u < 8; u++) y[u] += fv * Fw2[c*32 + ob + u];
  }
  #pragma unroll
  for (int u = 0; u < 8; u++) y[u] += Tw[s*33 + ob + u];
  sm = 0.f; sq = 0.f;
  #pragma unroll
  for (int u = 0; u < 8; u++){ sm += y[u]; sq += y[u]*y[u]; }
  sm += __shfl_xor(sm, 1); sq += __shfl_xor(sq, 1);
  sm += __shfl_xor(sm, 2); sq += __shfl_xor(sq, 2);
  float mean2 = sm * (1.f/32.f);
  float var2  = sq * (1.f/32.f) - mean2*mean2;
  float rinv2 = 1.0f / sqrtf(var2 + 1e-3f);
  float mv[8];
  #pragma unroll
  for (int u = 0; u < 8; u++){
    float v = (y[u] - mean2) * rinv2 * L2g[ob+u] + L2b[ob+u];
    v += __shfl_xor(v, 4);  v += __shfl_xor(v, 8);
    v += __shfl_xor(v, 16); v += __shfl_xor(v, 32);
    mv[u] = v * (1.f/16.f);
  }
  if (s == 0){
    #pragma unroll
    for (int u = 0; u < 8; u++) Tw[ob + u] = mv[u];
  }
  const int t = lane & 15;
  float hid = Rb1v[t];
  for (int o2 = 0; o2 < 32; o2++) hid += Tw[o2] * Rw1[o2*16 + t];
  hid = gelu_exact(hid) * Rw2[t];
  hid += __shfl_xor(hid, 1); hid += __shfl_xor(hid, 2);
  hid += __shfl_xor(hid, 4); hid += __shfl_xor(hid, 8);
  if (lane == 0) out[p] = hid + Rb2s[0];
}

extern "C" void kernel_launch(void* const* d_in, const int* in_sizes, int n_in,
                              void* d_out, int out_size, void* d_ws, size_t ws_size,
                              hipStream_t stream){
  const float* x    = (const float*)d_in[0];
  const float* adj  = (const float*)d_in[1];
  const float* pw   = (const float*)d_in[2];
  const float* pb   = (const float*)d_in[3];
  const float* g1w  = (const float*)d_in[4];
  const float* g1as = (const float*)d_in[5];
  const float* g1ad = (const float*)d_in[6];
  const float* g1b  = (const float*)d_in[7];
  const float* g2w  = (const float*)d_in[8];
  const float* g2as = (const float*)d_in[9];
  const float* g2ad = (const float*)d_in[10];
  const float* g2b  = (const float*)d_in[11];

  char* ws = (char*)d_ws;
  unsigned short* nlist = (unsigned short*)(ws + OFF_NBR);
  int*   cnt = (int*)(ws + OFF_CNT);
  float* hp1 = (float*)(ws + OFF_HP1);
  float* es1 = (float*)(ws + OFF_ES1);
  float* ed1 = (float*)(ws + OFF_ED1);
  float* hp2 = (float*)(ws + OFF_HP2);
  float* es2 = (float*)(ws + OFF_ES2);
  float* ed2 = (float*)(ws + OFF_ED2);

  TW tw;
  for (int t = 0; t < 20; t++) tw.p[t] = (const float*)d_in[12 + t];

  hipLaunchKernelGGL(k_nbr_pre1, dim3(NN/4 + 100), dim3(256), 0, stream,
                     adj, x, pw, pb, g1w, g1as, g1ad, nlist, cnt, hp1, es1, ed1);
  hipLaunchKernelGGL(k_gat1pre2, dim3(NROWS/64), dim3(256), 0, stream,
                     hp1, es1, ed1, nlist, cnt, g1b, g2w, g2as, g2ad, hp2, es2, ed2);
  hipLaunchKernelGGL(k_trans7, dim3(NSEQ/4), dim3(256), 0, stream,
                     hp2, es2, ed2, nlist, cnt, g2b, tw, (float*)d_out);
}